// Round 3
// baseline (893.467 us; speedup 1.0000x reference)
//
#include <hip/hip_runtime.h>
#include <hip/hip_bf16.h>

typedef unsigned short u16;
typedef __attribute__((ext_vector_type(8))) __bf16 bf16x8;
typedef __attribute__((ext_vector_type(8))) unsigned short u16x8;
typedef __attribute__((ext_vector_type(4))) float floatx4;
typedef __attribute__((ext_vector_type(16))) float floatx16;

#define AS1 __attribute__((address_space(1)))
#define AS3 __attribute__((address_space(3)))

__device__ __forceinline__ u16 f2bf(float f) {
  unsigned u = __float_as_uint(f);
  u += 0x7fffu + ((u >> 16) & 1u);   // round-to-nearest-even (inputs finite)
  return (u16)(u >> 16);
}

__device__ __forceinline__ void g2lds16(const u16* g, u16* l) {
  // 16B-wide async global->LDS; LDS dest is wave-uniform base + lane*16
  __builtin_amdgcn_global_load_lds((AS1 void*)g, (AS3 void*)l, 16, 0, 0);
}

// ---------------- fp32 -> bf16 convert (vectorized) ----------------
__global__ __launch_bounds__(256) void k_cvt_bf16(const float* __restrict__ s,
                                                  u16* __restrict__ d, long n) {
  long i = ((long)blockIdx.x * blockDim.x + threadIdx.x) * 8;
  long stride = (long)gridDim.x * blockDim.x * 8;
  for (; i < n; i += stride) {
    float4 a = *(const float4*)(s + i);
    float4 b = *(const float4*)(s + i + 4);
    u16x8 o;
    o[0] = f2bf(a.x); o[1] = f2bf(a.y); o[2] = f2bf(a.z); o[3] = f2bf(a.w);
    o[4] = f2bf(b.x); o[5] = f2bf(b.y); o[6] = f2bf(b.z); o[7] = f2bf(b.w);
    *(u16x8*)(d + i) = o;
  }
}

// ---------------- (Wk + Wv) -> bf16 ----------------
__global__ __launch_bounds__(256) void k_addcvt(const float* __restrict__ s0,
                                                const float* __restrict__ s1,
                                                u16* __restrict__ d, long n) {
  long i = ((long)blockIdx.x * blockDim.x + threadIdx.x) * 8;
  long stride = (long)gridDim.x * blockDim.x * 8;
  for (; i < n; i += stride) {
    float4 a0 = *(const float4*)(s0 + i);
    float4 a1 = *(const float4*)(s0 + i + 4);
    float4 b0 = *(const float4*)(s1 + i);
    float4 b1 = *(const float4*)(s1 + i + 4);
    u16x8 o;
    o[0] = f2bf(a0.x + b0.x); o[1] = f2bf(a0.y + b0.y);
    o[2] = f2bf(a0.z + b0.z); o[3] = f2bf(a0.w + b0.w);
    o[4] = f2bf(a1.x + b1.x); o[5] = f2bf(a1.y + b1.y);
    o[6] = f2bf(a1.z + b1.z); o[7] = f2bf(a1.w + b1.w);
    *(u16x8*)(d + i) = o;
  }
}

// ---------------- transpose + convert: src fp32 [R][C] -> dst bf16 [C][R] ----------------
__global__ __launch_bounds__(256) void k_tcvt(const float* __restrict__ s,
                                              u16* __restrict__ d, int R, int C) {
  __shared__ float t[32][33];
  const int lx = threadIdx.x, ly = threadIdx.y;
  const int bx = blockIdx.x * 32;  // col of src
  const int by = blockIdx.y * 32;  // row of src
  #pragma unroll
  for (int i = 0; i < 32; i += 8)
    t[ly + i][lx] = s[(size_t)(by + ly + i) * C + bx + lx];
  __syncthreads();
  #pragma unroll
  for (int i = 0; i < 32; i += 8)
    d[(size_t)(bx + ly + i) * R + by + lx] = f2bf(t[lx][ly + i]);
}

// ============ 256x256 8-wave pipelined bf16 GEMM: C = A @ Bt^T ============
// A [M][K], Bt [N][K], K % 64 == 0, M % 256 == 0, N % 256 == 0.
// MODE 0: bf16 out (ld=N). MODE 1: GEMM1 split epilogue (q / latent). MODE 2: fp32 out.
// LDS (dynamic 128KB): [buf2][op2][256 rows][64 k] bf16, XOR-swizzled 16B slots.
// Per K-tile: 4 phases (m-quarters). B fragments register-resident for the
// whole tile (read once: 8 b128); each phase reads 2 new A-frags (4 b128).
// All 4 half-tiles of t+1 staged at phase 0 of tile t -> vmcnt(0) at tile end
// waits on loads issued ~4 phases earlier (fully hidden).

#define MFMA16(a, b, c) c = __builtin_amdgcn_mfma_f32_16x16x32_bf16(a, b, c, 0, 0, 0)

#define STAGE(BUF, OP, RH, T) do {                                              \
    const u16* Gp_ = (OP) ? Bg : Ag;                                            \
    const u16* g0_ = Gp_ + (size_t)((RH) * 128 + srow) * K + (T) * 64 + scols;  \
    u16* L_ = ldsb + ((BUF) * 2 + (OP)) * 16384 + (RH) * 8192 + tid * 8;        \
    g2lds16(g0_, L_);                                                           \
    g2lds16(g0_ + (size_t)64 * K, L_ + 4096);                                   \
  } while (0)

#define RD_A2(MI, KS) \
  (*(const bf16x8*)(LA + ((wr * 128 + (MI) * 16 + fr) * 64 + ((((KS) * 32) + g8) ^ xr))))
#define RD_B2(NI, KS) \
  (*(const bf16x8*)(LB + ((wc * 64 + (NI) * 16 + fr) * 64 + ((((KS) * 32) + g8) ^ xr))))

#define PH_MFMA(MI0)                                         \
  __builtin_amdgcn_s_setprio(1);                             \
  MFMA16(a0[0], Br[0][0], acc[MI0][0]);                      \
  MFMA16(a1[0], Br[0][0], acc[(MI0) + 1][0]);                \
  MFMA16(a0[0], Br[1][0], acc[MI0][1]);                      \
  MFMA16(a1[0], Br[1][0], acc[(MI0) + 1][1]);                \
  MFMA16(a0[0], Br[2][0], acc[MI0][2]);                      \
  MFMA16(a1[0], Br[2][0], acc[(MI0) + 1][2]);                \
  MFMA16(a0[0], Br[3][0], acc[MI0][3]);                      \
  MFMA16(a1[0], Br[3][0], acc[(MI0) + 1][3]);                \
  MFMA16(a0[1], Br[0][1], acc[MI0][0]);                      \
  MFMA16(a1[1], Br[0][1], acc[(MI0) + 1][0]);                \
  MFMA16(a0[1], Br[1][1], acc[MI0][1]);                      \
  MFMA16(a1[1], Br[1][1], acc[(MI0) + 1][1]);                \
  MFMA16(a0[1], Br[2][1], acc[MI0][2]);                      \
  MFMA16(a1[1], Br[2][1], acc[(MI0) + 1][2]);                \
  MFMA16(a0[1], Br[3][1], acc[MI0][3]);                      \
  MFMA16(a1[1], Br[3][1], acc[(MI0) + 1][3]);                \
  __builtin_amdgcn_s_setprio(0)

template <int MODE>
__global__ __launch_bounds__(512, 2) void gemm8p(
    const u16* __restrict__ A, const u16* __restrict__ Bt,
    int M, int N, int K, int ntn,
    u16* __restrict__ Cb, float* __restrict__ Cf,
    const float* __restrict__ memp, float* __restrict__ latf, u16* __restrict__ latb) {
  extern __shared__ u16 ldsb[];   // [2][2][256*64]
  const int tid = threadIdx.x;
  const int lane = tid & 63;
  const int wid = tid >> 6;        // 8 waves: 2M x 4N
  const int wr = wid >> 2, wc = wid & 3;

  // bijective XCD-aware swizzle (m204)
  int bid = blockIdx.x;
  {
    const int nwg = gridDim.x;
    const int q = nwg >> 3, r = nwg & 7;
    const int xcd = bid & 7, idx = bid >> 3;
    bid = (xcd < r ? xcd * (q + 1) : r * (q + 1) + (xcd - r) * q) + idx;
  }
  const int mt = bid / ntn, nt = bid % ntn;
  const int m0 = mt * 256, n0 = nt * 256;
  const int NT = K >> 6;

  const int srow = tid >> 3;                       // staging row within 64-row inst
  const int scols = ((tid & 7) ^ (srow & 7)) * 8;  // pre-swizzled source col (u16)
  const int fr = lane & 15;
  const int g8 = (lane >> 4) * 8;
  const int xr = (lane & 7) * 8;                   // read-side XOR (u16 units)

  const u16* Ag = A + (size_t)m0 * K;
  const u16* Bg = Bt + (size_t)n0 * K;

  floatx4 acc[8][4];
  #pragma unroll
  for (int i = 0; i < 8; i++)
    #pragma unroll
    for (int j = 0; j < 4; j++) acc[i][j] = 0.0f;

  // prologue: stage tile 0 fully
  STAGE(0, 0, 0, 0);
  STAGE(0, 0, 1, 0);
  STAGE(0, 1, 0, 0);
  STAGE(0, 1, 1, 0);
  asm volatile("s_waitcnt vmcnt(0)" ::: "memory");
  __builtin_amdgcn_s_barrier();

  for (int t = 0; t < NT; ++t) {
    const int cur = t & 1;
    const int nxt = cur ^ 1;
    const u16* LA = ldsb + cur * 32768;
    const u16* LB = LA + 16384;
    bf16x8 Br[4][2];
    bf16x8 a0[2], a1[2];
    { // phase 0: read all B (8) + A m0,m1 (4); stage ALL of tile t+1 (8 loads)
      #pragma unroll
      for (int n = 0; n < 4; n++) { Br[n][0] = RD_B2(n, 0); Br[n][1] = RD_B2(n, 1); }
      a0[0] = RD_A2(0, 0); a0[1] = RD_A2(0, 1);
      a1[0] = RD_A2(1, 0); a1[1] = RD_A2(1, 1);
      if (t + 1 < NT) {
        STAGE(nxt, 0, 0, t + 1);
        STAGE(nxt, 0, 1, t + 1);
        STAGE(nxt, 1, 0, t + 1);
        STAGE(nxt, 1, 1, t + 1);
      }
      asm volatile("s_waitcnt lgkmcnt(8)" ::: "memory");
      __builtin_amdgcn_s_barrier();
      asm volatile("s_waitcnt lgkmcnt(0)" ::: "memory");
      PH_MFMA(0);
      __builtin_amdgcn_s_barrier();
    }
    { // phase 1: A m2,m3
      a0[0] = RD_A2(2, 0); a0[1] = RD_A2(2, 1);
      a1[0] = RD_A2(3, 0); a1[1] = RD_A2(3, 1);
      __builtin_amdgcn_s_barrier();
      asm volatile("s_waitcnt lgkmcnt(0)" ::: "memory");
      PH_MFMA(2);
      __builtin_amdgcn_s_barrier();
    }
    { // phase 2: A m4,m5
      a0[0] = RD_A2(4, 0); a0[1] = RD_A2(4, 1);
      a1[0] = RD_A2(5, 0); a1[1] = RD_A2(5, 1);
      __builtin_amdgcn_s_barrier();
      asm volatile("s_waitcnt lgkmcnt(0)" ::: "memory");
      PH_MFMA(4);
      __builtin_amdgcn_s_barrier();
    }
    { // phase 3: A m6,m7; tile-end vmcnt(0) (loads issued at P0 -> hidden)
      a0[0] = RD_A2(6, 0); a0[1] = RD_A2(6, 1);
      a1[0] = RD_A2(7, 0); a1[1] = RD_A2(7, 1);
      __builtin_amdgcn_s_barrier();
      asm volatile("s_waitcnt lgkmcnt(0)" ::: "memory");
      PH_MFMA(6);
      asm volatile("s_waitcnt vmcnt(0)" ::: "memory");
      __builtin_amdgcn_s_barrier();
    }
  }

  // epilogue
  #pragma unroll
  for (int mi = 0; mi < 8; mi++) {
    const int mb = m0 + wr * 128 + mi * 16 + ((lane >> 4) * 4);
    #pragma unroll
    for (int ni = 0; ni < 4; ni++) {
      const int cb = n0 + wc * 64 + ni * 16 + (lane & 15);
      #pragma unroll
      for (int r = 0; r < 4; r++) {
        const int m = mb + r;
        const float v = acc[mi][ni][r];
        if (MODE == 0) {
          Cb[(size_t)m * N + cb] = f2bf(v);
        } else if (MODE == 1) {
          if (n0 < 1024) {
            Cb[(size_t)m * 1024 + cb] = f2bf(v);   // q, ld=1024
          } else {
            int lc = cb - 1024;                     // latent col 0..255
            float lv = (v + memp[(size_t)m * 256 + lc]) * 0.5f;
            latf[(size_t)m * 256 + lc] = lv;        // fp32 output #2
            latb[(size_t)m * 256 + lc] = f2bf(lv);  // bf16 for GEMM2
          }
        } else {
          Cf[(size_t)m * N + cb] = v;
        }
      }
    }
  }
}

// ---------------- attention: per block = (4 heads of one batch) ----------------
__global__ __launch_bounds__(256) void k_attn(const u16* __restrict__ KV, u16* Q) {
  __shared__ u16 Qs[4][32][72];   // reused as P (32x40) per wave after QK^T
  __shared__ u16 Ks[4][32][72];
  __shared__ u16 Vt[4][64][40];   // v transposed: [head][d][key]
  const int tid = threadIdx.x;
  const int hg = blockIdx.x;      // head group 0..3
  const int b = blockIdx.y;       // batch 0..2047
  const long tok0 = (long)b * 32;

  {
    const int t = tid >> 3, ci = tid & 7;
    const int hd = ci >> 1, c0 = (ci & 1) * 32;
    const u16* qrow = Q + (tok0 + t) * 1024 + hg * 256 + ci * 32;
    #pragma unroll
    for (int u = 0; u < 4; u++)
      *(u16x8*)&Qs[hd][t][c0 + u * 8] = *(const u16x8*)(qrow + u * 8);
    const u16* krow = KV + (tok0 + t) * 2048 + hg * 256 + ci * 32;
    #pragma unroll
    for (int u = 0; u < 4; u++)
      *(u16x8*)&Ks[hd][t][c0 + u * 8] = *(const u16x8*)(krow + u * 8);
    const u16* vrow = KV + (tok0 + t) * 2048 + 1024 + hg * 256 + ci * 32;
    #pragma unroll
    for (int u = 0; u < 4; u++) {
      u16x8 v = *(const u16x8*)(vrow + u * 8);
      #pragma unroll
      for (int j = 0; j < 8; j++) Vt[hd][c0 + u * 8 + j][t] = v[j];
    }
  }
  __syncthreads();

  const int w = tid >> 6;
  const int lane = tid & 63;
  const int col = lane & 31, hi = lane >> 5;

  floatx16 S;
  #pragma unroll
  for (int r = 0; r < 16; r++) S[r] = 0.0f;
  #pragma unroll
  for (int kc = 0; kc < 4; kc++) {
    bf16x8 aq = *(const bf16x8*)&Qs[w][col][kc * 16 + hi * 8];
    bf16x8 bk = *(const bf16x8*)&Ks[w][col][kc * 16 + hi * 8];
    S = __builtin_amdgcn_mfma_f32_32x32x16_bf16(aq, bk, S, 0, 0, 0);
  }

  u16* Pw = &Qs[w][0][0];
  float pr[16];
  #pragma unroll
  for (int r = 0; r < 16; r++) {
    float sc = S[r] * 0.03125f;    // 1/sqrt(1024)
    float mx = sc;
    #pragma unroll
    for (int off = 16; off >= 1; off >>= 1) mx = fmaxf(mx, __shfl_xor(mx, off, 64));
    float e = __expf(sc - mx);
    float sm = e;
    #pragma unroll
    for (int off = 16; off >= 1; off >>= 1) sm += __shfl_xor(sm, off, 64);
    pr[r] = e / sm;
  }
  #pragma unroll
  for (int r = 0; r < 16; r++) {
    int row = (r & 3) + 8 * (r >> 2) + 4 * hi;
    Pw[row * 40 + col] = f2bf(pr[r]);
  }
  __syncthreads();

  floatx16 c0v, c1v;
  #pragma unroll
  for (int r = 0; r < 16; r++) { c0v[r] = 0.0f; c1v[r] = 0.0f; }
  #pragma unroll
  for (int kc = 0; kc < 2; kc++) {
    bf16x8 ap = *(const bf16x8*)&Pw[col * 40 + kc * 16 + hi * 8];
    bf16x8 bv0 = *(const bf16x8*)&Vt[w][col][kc * 16 + hi * 8];
    bf16x8 bv1 = *(const bf16x8*)&Vt[w][32 + col][kc * 16 + hi * 8];
    c0v = __builtin_amdgcn_mfma_f32_32x32x16_bf16(ap, bv0, c0v, 0, 0, 0);
    c1v = __builtin_amdgcn_mfma_f32_32x32x16_bf16(ap, bv1, c1v, 0, 0, 0);
  }
  #pragma unroll
  for (int r = 0; r < 16; r++) {
    int row = (r & 3) + 8 * (r >> 2) + 4 * hi;
    u16* orow = Q + (tok0 + row) * 1024 + hg * 256 + w * 64;
    orow[col] = f2bf(c0v[r]);
    orow[col + 32] = f2bf(c1v[r]);
  }
}

extern "C" void kernel_launch(void* const* d_in, const int* in_sizes, int n_in,
                              void* d_out, int out_size, void* d_ws, size_t ws_size,
                              hipStream_t stream) {
  const float* x    = (const float*)d_in[0];
  const float* mem  = (const float*)d_in[1];
  const float* W_q  = (const float*)d_in[2];
  const float* W_k  = (const float*)d_in[3];
  const float* W_v  = (const float*)d_in[4];
  const float* W_o  = (const float*)d_in[5];
  const float* W_dn = (const float*)d_in[6];
  const float* W_uk = (const float*)d_in[7];
  const float* W_uv = (const float*)d_in[8];
  float* out  = (float*)d_out;
  float* latf = out + (size_t)67108864;   // latent_kv fp32 output

  char* wp = (char*)d_ws;
  u16* Qb  = (u16*)wp; wp += (size_t)65536 * 1024 * 2;  // q / ctx bf16
  u16* Lb  = (u16*)wp; wp += (size_t)65536 * 256 * 2;   // latent bf16
  u16* WAt = (u16*)wp; wp += (size_t)1280 * 1024 * 2;   // [W_q | W_kvd]^T
  u16* WBt = (u16*)wp; wp += (size_t)2048 * 256 * 2;    // [W_up_k | W_up_v]^T
  u16* Wot = (u16*)wp; wp += (size_t)1024 * 1024 * 2;   // W_o^T
  u16* Wdt = (u16*)wp; wp += (size_t)256 * 1024 * 2;    // W_down^T
  u16* Wkv = (u16*)wp; wp += (size_t)1024 * 1024 * 2;   // (Wk+Wv) bf16

  u16* Xb  = (u16*)d_out;  // x bf16 (aliased; dead before final GEMM)
  u16* KVb = (u16*)d_out;  // kv_rec bf16 (overwrites Xb after GEMM1)

  (void)hipFuncSetAttribute(reinterpret_cast<const void*>(&gemm8p<0>),
                            hipFuncAttributeMaxDynamicSharedMemorySize, 131072);
  (void)hipFuncSetAttribute(reinterpret_cast<const void*>(&gemm8p<1>),
                            hipFuncAttributeMaxDynamicSharedMemorySize, 131072);
  (void)hipFuncSetAttribute(reinterpret_cast<const void*>(&gemm8p<2>),
                            hipFuncAttributeMaxDynamicSharedMemorySize, 131072);

  dim3 b256(256);
  dim3 b512(512);
  dim3 tb(32, 8);
  k_cvt_bf16<<<4096, b256, 0, stream>>>(x, Xb, (long)67108864);
  k_addcvt<<<512, b256, 0, stream>>>(W_k, W_v, Wkv, (long)1048576);
  k_tcvt<<<dim3(32, 32), tb, 0, stream>>>(W_q, WAt, 1024, 1024);
  k_tcvt<<<dim3(8, 32),  tb, 0, stream>>>(W_dn, Wdt, 1024, 256);
  k_tcvt<<<dim3(32, 8),  tb, 0, stream>>>(W_uk, WBt, 256, 1024);
  k_tcvt<<<dim3(32, 8),  tb, 0, stream>>>(W_uv, WBt + (size_t)1024 * 256, 256, 1024);
  k_tcvt<<<dim3(32, 32), tb, 0, stream>>>(W_o, Wot, 1024, 1024);

  // W_kvd^T = Wdt @ Wkv^T -> WAt rows 1024..1279
  gemm8p<0><<<4, b512, 131072, stream>>>(
      Wdt, Wkv, 256, 1024, 1024, 4, WAt + (size_t)1024 * 1024,
      nullptr, nullptr, nullptr, nullptr);

  // GEMM1: [q | latent_pre] = x @ [W_q | W_kvd]
  gemm8p<1><<<1280, b512, 131072, stream>>>(
      Xb, WAt, 65536, 1280, 1024, 5, Qb, nullptr, mem, latf, Lb);

  // GEMM2: [k_rec | v_rec] = latent @ [W_up_k | W_up_v]
  gemm8p<0><<<2048, b512, 131072, stream>>>(
      Lb, WBt, 65536, 2048, 256, 8, KVb, nullptr, nullptr, nullptr, nullptr);

  // attention (ctx overwrites Qb in place)
  k_attn<<<dim3(4, 2048), b256, 0, stream>>>(KVb, Qb);

  // GEMM3: out = ctx @ W_o (fp32)
  gemm8p<2><<<1024, b512, 131072, stream>>>(
      Qb, Wot, 65536, 1024, 1024, 4, nullptr, out, nullptr, nullptr, nullptr);
}

// Round 4
// 798.489 us; speedup vs baseline: 1.1189x; 1.1189x over previous
//
#include <hip/hip_runtime.h>
#include <hip/hip_bf16.h>

typedef unsigned short u16;
typedef __attribute__((ext_vector_type(8))) __bf16 bf16x8;
typedef __attribute__((ext_vector_type(8))) unsigned short u16x8;
typedef __attribute__((ext_vector_type(4))) float floatx4;
typedef __attribute__((ext_vector_type(16))) float floatx16;

#define AS1 __attribute__((address_space(1)))
#define AS3 __attribute__((address_space(3)))

__device__ __forceinline__ u16 f2bf(float f) {
  unsigned u = __float_as_uint(f);
  u += 0x7fffu + ((u >> 16) & 1u);   // round-to-nearest-even (inputs finite)
  return (u16)(u >> 16);
}

__device__ __forceinline__ void g2lds16(const u16* g, u16* l) {
  // 16B-wide async global->LDS; LDS dest is wave-uniform base + lane*16
  __builtin_amdgcn_global_load_lds((AS1 void*)g, (AS3 void*)l, 16, 0, 0);
}

// ---------------- fp32 -> bf16 convert (vectorized) ----------------
__global__ __launch_bounds__(256) void k_cvt_bf16(const float* __restrict__ s,
                                                  u16* __restrict__ d, long n) {
  long i = ((long)blockIdx.x * blockDim.x + threadIdx.x) * 8;
  long stride = (long)gridDim.x * blockDim.x * 8;
  for (; i < n; i += stride) {
    float4 a = *(const float4*)(s + i);
    float4 b = *(const float4*)(s + i + 4);
    u16x8 o;
    o[0] = f2bf(a.x); o[1] = f2bf(a.y); o[2] = f2bf(a.z); o[3] = f2bf(a.w);
    o[4] = f2bf(b.x); o[5] = f2bf(b.y); o[6] = f2bf(b.z); o[7] = f2bf(b.w);
    *(u16x8*)(d + i) = o;
  }
}

// ---------------- (Wk + Wv) -> bf16 ----------------
__global__ __launch_bounds__(256) void k_addcvt(const float* __restrict__ s0,
                                                const float* __restrict__ s1,
                                                u16* __restrict__ d, long n) {
  long i = ((long)blockIdx.x * blockDim.x + threadIdx.x) * 8;
  long stride = (long)gridDim.x * blockDim.x * 8;
  for (; i < n; i += stride) {
    float4 a0 = *(const float4*)(s0 + i);
    float4 a1 = *(const float4*)(s0 + i + 4);
    float4 b0 = *(const float4*)(s1 + i);
    float4 b1 = *(const float4*)(s1 + i + 4);
    u16x8 o;
    o[0] = f2bf(a0.x + b0.x); o[1] = f2bf(a0.y + b0.y);
    o[2] = f2bf(a0.z + b0.z); o[3] = f2bf(a0.w + b0.w);
    o[4] = f2bf(a1.x + b1.x); o[5] = f2bf(a1.y + b1.y);
    o[6] = f2bf(a1.z + b1.z); o[7] = f2bf(a1.w + b1.w);
    *(u16x8*)(d + i) = o;
  }
}

// ---------------- transpose + convert: src fp32 [R][C] -> dst bf16 [C][R] ----------------
__global__ __launch_bounds__(256) void k_tcvt(const float* __restrict__ s,
                                              u16* __restrict__ d, int R, int C) {
  __shared__ float t[32][33];
  const int lx = threadIdx.x, ly = threadIdx.y;
  const int bx = blockIdx.x * 32;  // col of src
  const int by = blockIdx.y * 32;  // row of src
  #pragma unroll
  for (int i = 0; i < 32; i += 8)
    t[ly + i][lx] = s[(size_t)(by + ly + i) * C + bx + lx];
  __syncthreads();
  #pragma unroll
  for (int i = 0; i < 32; i += 8)
    d[(size_t)(bx + ly + i) * R + by + lx] = f2bf(t[lx][ly + i]);
}

// ============ 128x128 4-wave bf16 GEMM (m97 structure + T2 swizzle + T1) ============
// C[m][n] = sum_k A[m][k] * Bt[n][k].  K%64==0, M%128==0, N%128==0.
// MODE 0: bf16 out (ld=N). MODE 1: GEMM1 split epilogue (q / latent). MODE 2: fp32 out.
// 32 KB static LDS, single-buffered (m97): TLP (3 blocks/CU) hides the drain.
// LDS swizzle: LDS[row][c8] holds global[row][c8 ^ (row&7)] (16B granules) so the
// fragment read (16 lanes = 16 rows at same k) spreads across 8 banks (2-way = free).

#define MFMA16(a, b, c) c = __builtin_amdgcn_mfma_f32_16x16x32_bf16(a, b, c, 0, 0, 0)

template <int MODE>
__global__ __launch_bounds__(256, 3) void gemm128(
    const u16* __restrict__ A, const u16* __restrict__ Bt,
    int M, int N, int K, int ntn,
    u16* __restrict__ Cb, float* __restrict__ Cf,
    const float* __restrict__ memp, float* __restrict__ latf, u16* __restrict__ latb) {
  __shared__ u16 As[128 * 64];
  __shared__ u16 Bs[128 * 64];
  const int tid = threadIdx.x;
  const int lane = tid & 63;
  const int wid = tid >> 6;          // 4 waves: 2x2
  const int wr = wid >> 1, wc = wid & 1;

  // bijective XCD-aware swizzle (m204): consecutive logical bids -> same XCD
  int bid = blockIdx.x;
  {
    const int nwg = gridDim.x;
    const int q = nwg >> 3, r = nwg & 7;
    const int xcd = bid & 7, idx = bid >> 3;
    bid = (xcd < r ? xcd * (q + 1) : r * (q + 1) + (xcd - r) * q) + idx;
  }
  const int mt = bid / ntn, nt = bid % ntn;
  const int m0 = mt * 128, n0 = nt * 128;

  const int fr = lane & 15;
  const int g8 = (lane >> 4) * 8;
  const int xr = (lane & 7) * 8;     // read-side XOR (u16 units); row&7 == lane&7

  floatx4 acc[4][4];
  #pragma unroll
  for (int i = 0; i < 4; i++)
    #pragma unroll
    for (int j = 0; j < 4; j++) acc[i][j] = 0.0f;

  const u16* Ag0 = A + (size_t)m0 * K;
  const u16* Bg0 = Bt + (size_t)n0 * K;

  for (int kt = 0; kt < K; kt += 64) {
    #pragma unroll
    for (int p = 0; p < 4; p++) {
      int ci = p * 256 + tid;
      int row = ci >> 3;
      int kc = ((ci & 7) ^ (row & 7)) * 8;   // pre-swizzled source col
      g2lds16(Ag0 + (size_t)row * K + kt + kc, &As[ci * 8]);
    }
    #pragma unroll
    for (int p = 0; p < 4; p++) {
      int ci = p * 256 + tid;
      int row = ci >> 3;
      int kc = ((ci & 7) ^ (row & 7)) * 8;
      g2lds16(Bg0 + (size_t)row * K + kt + kc, &Bs[ci * 8]);
    }
    __syncthreads();
    #pragma unroll
    for (int kk = 0; kk < 64; kk += 32) {
      const int koff = kk + g8;
      bf16x8 af[4], bfv[4];
      #pragma unroll
      for (int i = 0; i < 4; i++)
        af[i] = *(const bf16x8*)&As[(wr * 64 + i * 16 + fr) * 64 + (koff ^ xr)];
      #pragma unroll
      for (int j = 0; j < 4; j++)
        bfv[j] = *(const bf16x8*)&Bs[(wc * 64 + j * 16 + fr) * 64 + (koff ^ xr)];
      #pragma unroll
      for (int i = 0; i < 4; i++)
        #pragma unroll
        for (int j = 0; j < 4; j++)
          MFMA16(af[i], bfv[j], acc[i][j]);
    }
    __syncthreads();
  }

  #pragma unroll
  for (int i = 0; i < 4; i++) {
    const int mb = m0 + wr * 64 + i * 16 + ((lane >> 4) * 4);
    #pragma unroll
    for (int j = 0; j < 4; j++) {
      const int cb = n0 + wc * 64 + j * 16 + (lane & 15);
      #pragma unroll
      for (int r = 0; r < 4; r++) {
        const int m = mb + r;
        const float v = acc[i][j][r];
        if (MODE == 0) {
          Cb[(size_t)m * N + cb] = f2bf(v);
        } else if (MODE == 1) {
          if (n0 < 1024) {
            Cb[(size_t)m * 1024 + cb] = f2bf(v);   // q, ld=1024
          } else {
            int lc = cb - 1024;                     // latent col 0..255
            float lv = (v + memp[(size_t)m * 256 + lc]) * 0.5f;
            latf[(size_t)m * 256 + lc] = lv;        // fp32 output #2
            latb[(size_t)m * 256 + lc] = f2bf(lv);  // bf16 for GEMM2
          }
        } else {
          Cf[(size_t)m * N + cb] = v;
        }
      }
    }
  }
}

// ---------------- attention: per block = (4 heads of one batch) ----------------
__global__ __launch_bounds__(256) void k_attn(const u16* __restrict__ KV, u16* Q) {
  __shared__ u16 Qs[4][32][72];   // reused as P (32x40) per wave after QK^T
  __shared__ u16 Ks[4][32][72];
  __shared__ u16 Vt[4][64][40];   // v transposed: [head][d][key]
  const int tid = threadIdx.x;
  const int hg = blockIdx.x;      // head group 0..3
  const int b = blockIdx.y;       // batch 0..2047
  const long tok0 = (long)b * 32;

  {
    const int t = tid >> 3, ci = tid & 7;
    const int hd = ci >> 1, c0 = (ci & 1) * 32;
    const u16* qrow = Q + (tok0 + t) * 1024 + hg * 256 + ci * 32;
    #pragma unroll
    for (int u = 0; u < 4; u++)
      *(u16x8*)&Qs[hd][t][c0 + u * 8] = *(const u16x8*)(qrow + u * 8);
    const u16* krow = KV + (tok0 + t) * 2048 + hg * 256 + ci * 32;
    #pragma unroll
    for (int u = 0; u < 4; u++)
      *(u16x8*)&Ks[hd][t][c0 + u * 8] = *(const u16x8*)(krow + u * 8);
    const u16* vrow = KV + (tok0 + t) * 2048 + 1024 + hg * 256 + ci * 32;
    #pragma unroll
    for (int u = 0; u < 4; u++) {
      u16x8 v = *(const u16x8*)(vrow + u * 8);
      #pragma unroll
      for (int j = 0; j < 8; j++) Vt[hd][c0 + u * 8 + j][t] = v[j];
    }
  }
  __syncthreads();

  const int w = tid >> 6;
  const int lane = tid & 63;
  const int col = lane & 31, hi = lane >> 5;

  floatx16 S;
  #pragma unroll
  for (int r = 0; r < 16; r++) S[r] = 0.0f;
  #pragma unroll
  for (int kc = 0; kc < 4; kc++) {
    bf16x8 aq = *(const bf16x8*)&Qs[w][col][kc * 16 + hi * 8];
    bf16x8 bk = *(const bf16x8*)&Ks[w][col][kc * 16 + hi * 8];
    S = __builtin_amdgcn_mfma_f32_32x32x16_bf16(aq, bk, S, 0, 0, 0);
  }

  u16* Pw = &Qs[w][0][0];
  float pr[16];
  #pragma unroll
  for (int r = 0; r < 16; r++) {
    float sc = S[r] * 0.03125f;    // 1/sqrt(1024)
    float mx = sc;
    #pragma unroll
    for (int off = 16; off >= 1; off >>= 1) mx = fmaxf(mx, __shfl_xor(mx, off, 64));
    float e = __expf(sc - mx);
    float sm = e;
    #pragma unroll
    for (int off = 16; off >= 1; off >>= 1) sm += __shfl_xor(sm, off, 64);
    pr[r] = e / sm;
  }
  #pragma unroll
  for (int r = 0; r < 16; r++) {
    int row = (r & 3) + 8 * (r >> 2) + 4 * hi;
    Pw[row * 40 + col] = f2bf(pr[r]);
  }
  __syncthreads();

  floatx16 c0v, c1v;
  #pragma unroll
  for (int r = 0; r < 16; r++) { c0v[r] = 0.0f; c1v[r] = 0.0f; }
  #pragma unroll
  for (int kc = 0; kc < 2; kc++) {
    bf16x8 ap = *(const bf16x8*)&Pw[col * 40 + kc * 16 + hi * 8];
    bf16x8 bv0 = *(const bf16x8*)&Vt[w][col][kc * 16 + hi * 8];
    bf16x8 bv1 = *(const bf16x8*)&Vt[w][32 + col][kc * 16 + hi * 8];
    c0v = __builtin_amdgcn_mfma_f32_32x32x16_bf16(ap, bv0, c0v, 0, 0, 0);
    c1v = __builtin_amdgcn_mfma_f32_32x32x16_bf16(ap, bv1, c1v, 0, 0, 0);
  }
  #pragma unroll
  for (int r = 0; r < 16; r++) {
    int row = (r & 3) + 8 * (r >> 2) + 4 * hi;
    u16* orow = Q + (tok0 + row) * 1024 + hg * 256 + w * 64;
    orow[col] = f2bf(c0v[r]);
    orow[col + 32] = f2bf(c1v[r]);
  }
}

extern "C" void kernel_launch(void* const* d_in, const int* in_sizes, int n_in,
                              void* d_out, int out_size, void* d_ws, size_t ws_size,
                              hipStream_t stream) {
  const float* x    = (const float*)d_in[0];
  const float* mem  = (const float*)d_in[1];
  const float* W_q  = (const float*)d_in[2];
  const float* W_k  = (const float*)d_in[3];
  const float* W_v  = (const float*)d_in[4];
  const float* W_o  = (const float*)d_in[5];
  const float* W_dn = (const float*)d_in[6];
  const float* W_uk = (const float*)d_in[7];
  const float* W_uv = (const float*)d_in[8];
  float* out  = (float*)d_out;
  float* latf = out + (size_t)67108864;   // latent_kv fp32 output

  char* wp = (char*)d_ws;
  u16* Qb  = (u16*)wp; wp += (size_t)65536 * 1024 * 2;  // q / ctx bf16
  u16* Lb  = (u16*)wp; wp += (size_t)65536 * 256 * 2;   // latent bf16
  u16* WAt = (u16*)wp; wp += (size_t)1280 * 1024 * 2;   // [W_q | W_kvd]^T
  u16* WBt = (u16*)wp; wp += (size_t)2048 * 256 * 2;    // [W_up_k | W_up_v]^T
  u16* Wot = (u16*)wp; wp += (size_t)1024 * 1024 * 2;   // W_o^T
  u16* Wdt = (u16*)wp; wp += (size_t)256 * 1024 * 2;    // W_down^T
  u16* Wkv = (u16*)wp; wp += (size_t)1024 * 1024 * 2;   // (Wk+Wv) bf16

  u16* Xb  = (u16*)d_out;  // x bf16 (aliased; dead before final GEMM)
  u16* KVb = (u16*)d_out;  // kv_rec bf16 (overwrites Xb after GEMM1)

  dim3 b256(256);
  dim3 tb(32, 8);
  k_cvt_bf16<<<4096, b256, 0, stream>>>(x, Xb, (long)67108864);
  k_addcvt<<<512, b256, 0, stream>>>(W_k, W_v, Wkv, (long)1048576);
  k_tcvt<<<dim3(32, 32), tb, 0, stream>>>(W_q, WAt, 1024, 1024);
  k_tcvt<<<dim3(8, 32),  tb, 0, stream>>>(W_dn, Wdt, 1024, 256);
  k_tcvt<<<dim3(32, 8),  tb, 0, stream>>>(W_uk, WBt, 256, 1024);
  k_tcvt<<<dim3(32, 8),  tb, 0, stream>>>(W_uv, WBt + (size_t)1024 * 256, 256, 1024);
  k_tcvt<<<dim3(32, 32), tb, 0, stream>>>(W_o, Wot, 1024, 1024);

  // W_kvd^T = Wdt @ Wkv^T -> WAt rows 1024..1279  (M=256, N=1024, 16 blocks)
  gemm128<0><<<16, b256, 0, stream>>>(
      Wdt, Wkv, 256, 1024, 1024, 8, WAt + (size_t)1024 * 1024,
      nullptr, nullptr, nullptr, nullptr);

  // GEMM1: [q | latent_pre] = x @ [W_q | W_kvd]   (512 x 10 tiles)
  gemm128<1><<<5120, b256, 0, stream>>>(
      Xb, WAt, 65536, 1280, 1024, 10, Qb, nullptr, mem, latf, Lb);

  // GEMM2: [k_rec | v_rec] = latent @ [W_up_k | W_up_v]   (512 x 16 tiles)
  gemm128<0><<<8192, b256, 0, stream>>>(
      Lb, WBt, 65536, 2048, 256, 16, KVb, nullptr, nullptr, nullptr, nullptr);

  // attention (ctx overwrites Qb in place)
  k_attn<<<dim3(4, 2048), b256, 0, stream>>>(KVb, Qb);

  // GEMM3: out = ctx @ W_o (fp32)   (512 x 8 tiles)
  gemm128<2><<<4096, b256, 0, stream>>>(
      Qb, Wot, 65536, 1024, 1024, 8, nullptr, out, nullptr, nullptr, nullptr);
}